// Round 9
// baseline (105.609 us; speedup 1.0000x reference)
//
#include <hip/hip_runtime.h>
#include <hip/hip_bf16.h>

// B=16, C=512, L=1024.
// score[b,i,j] = sum_c k[b,c,i]*q[b,c,j] / 32 ; P = softmax over b (axis=0!)
// out[b,c,j] = sum_i v[b,c,i]*P[b,i,j]
// Pipeline (all bf16 MFMA, fp32 accum):
//   K0 transpose_convert: q,k f32 [b][c][l] -> qT,kT bf16 [b][l][c]
//   K1 gemm_glds: S'[b][j][i] = (qT . kT^T)/32, bf16   (batched 1024x1024x512)
//   K3 convert_v: v f32 -> vB bf16 [b][c][i]  (overlays qT, dead after K1)
//   K2 softmax_b: in-place softmax over b (16 per (j,i)) on S'
//   K4 gemm_glds: out[b][c][j] = vB . P^T, f32         (batched 512x1024x1024)
// GEMM: 128x128 tile, BK=32, 3-deep LDS ring (48 KiB -> 3 blocks/CU),
// global_load_lds w=16, XOR swizzle slot^=(row&3) on source AND ds_read (rule 21).
// T4 schedule: STAGE(s+2) -> s_waitcnt vmcnt(N) + s_barrier -> ds_read+MFMA(s)
// -> s_barrier. vmcnt never drained to 0 in steady state.

#define LN 1024
#define CC 512
#define BN 16

typedef __attribute__((ext_vector_type(8))) short bf16x8;
typedef __attribute__((ext_vector_type(4))) float f32x4;

static __device__ __forceinline__ unsigned short f2bf(float x) {
  union { float f; unsigned u; } un; un.f = x;
  unsigned r = un.u + 0x7fffu + ((un.u >> 16) & 1u);   // RNE
  return (unsigned short)(r >> 16);
}
static __device__ __forceinline__ float bf2f(unsigned short h) {
  union { unsigned u; float f; } un; un.u = ((unsigned)h) << 16; return un.f;
}

// ---------------- K0: transpose-convert q,k (f32 [b][c][l]) -> bf16 [b][l][c]
__global__ __launch_bounds__(256) void transpose_convert(
    const float* __restrict__ q, const float* __restrict__ k,
    unsigned short* __restrict__ qT, unsigned short* __restrict__ kT) {
  __shared__ float tile[32][33];
  const int b   = blockIdx.z >> 1;
  const int mat = blockIdx.z & 1;
  const float* src = mat ? k : q;
  unsigned short* dst = mat ? kT : qT;
  const int l0 = blockIdx.x * 32, c0 = blockIdx.y * 32;
  const int t = threadIdx.x;
  const int ll = t & 31, cbase = t >> 5;
  const float* sp = src + ((size_t)b * CC + c0) * LN + l0;
#pragma unroll
  for (int r = 0; r < 4; ++r) {
    int cc = cbase + r * 8;
    tile[cc][ll] = sp[(size_t)cc * LN + ll];
  }
  __syncthreads();
  const int co = t & 31, lbase = t >> 5;
  unsigned short* dp = dst + ((size_t)b * LN + l0) * CC + c0;
#pragma unroll
  for (int r = 0; r < 4; ++r) {
    int lo = lbase + r * 8;
    dp[(size_t)lo * CC + co] = f2bf(tile[co][lo]);
  }
}

// ---------------- batched GEMM, both operands K-contiguous:
// C[row][col] = scale * sum_k A[row][k] * B[col][k]
// 128x128 tile, BK=32, 3-ring, 4 waves 2x2, 4x4 frags of 16x16x32.
template<int KD, int LDAv, int LDBv, int LDCv, bool OBF>
__global__ __launch_bounds__(256, 3) void gemm_glds(
    const unsigned short* __restrict__ A, const unsigned short* __restrict__ B,
    void* __restrict__ Cv, float scale,
    size_t strideA, size_t strideB, size_t strideC) {
  __shared__ unsigned short As[3][128 * 32];   // 3 x 8 KiB
  __shared__ unsigned short Bs[3][128 * 32];   // 3 x 8 KiB  (total 48 KiB)
  const int bz = blockIdx.z;
  const unsigned short* Ab = A + (size_t)bz * strideA;
  const unsigned short* Bb = B + (size_t)bz * strideB;
  const int tm = blockIdx.y, tn = blockIdx.x;
  const int t = threadIdx.x, w = t >> 6, l = t & 63;
  const int wr = w >> 1, wc = w & 1;
  const int lr = l & 15, lks = l >> 4;         // k-slot 0..3 (8 shorts each)

  f32x4 acc[4][4];
#pragma unroll
  for (int m = 0; m < 4; ++m)
#pragma unroll
    for (int n = 0; n < 4; ++n) acc[m][n] = (f32x4){0.f, 0.f, 0.f, 0.f};

  // staging: thread t covers (row = qq*64 + t/4, phys slot = t&3); LDS dest
  // linear (glds requires it); global source column carries the swizzle.
  const int srow = t >> 2;        // 0..63
  const int sslot = t & 3;

  auto STAGE = [&](int buf, int step) {   // 4 glds instructions per wave
    const int c0 = step * 32;
#pragma unroll
    for (int qq = 0; qq < 2; ++qq) {
      const int row = qq * 64 + srow;
      const unsigned short* ga =
          Ab + (size_t)(tm * 128 + row) * LDAv + c0 + ((sslot ^ (row & 3)) * 8);
      __builtin_amdgcn_global_load_lds(
          (const __attribute__((address_space(1))) void*)ga,
          (__attribute__((address_space(3))) void*)&As[buf][qq * 2048 + t * 8],
          16, 0, 0);
    }
#pragma unroll
    for (int qq = 0; qq < 2; ++qq) {
      const int row = qq * 64 + srow;
      const unsigned short* gb =
          Bb + (size_t)(tn * 128 + row) * LDBv + c0 + ((sslot ^ (row & 3)) * 8);
      __builtin_amdgcn_global_load_lds(
          (const __attribute__((address_space(1))) void*)gb,
          (__attribute__((address_space(3))) void*)&Bs[buf][qq * 2048 + t * 8],
          16, 0, 0);
    }
  };

  const int NSTEP = KD / 32;
  STAGE(0, 0);
  STAGE(1, 1);

#pragma unroll 1
  for (int s = 0; s < NSTEP; ++s) {
    if (s + 2 < NSTEP) STAGE((s + 2) % 3, s + 2);
    // Wait until THIS wave's step-s loads landed (counted, never full drain in
    // steady state), then barrier => ALL waves' step-s loads landed.
    if (s + 2 < NSTEP) {
      asm volatile("s_waitcnt vmcnt(8)\n\ts_barrier" ::: "memory");
    } else if (s + 2 == NSTEP) {
      asm volatile("s_waitcnt vmcnt(4)\n\ts_barrier" ::: "memory");
    } else {
      asm volatile("s_waitcnt vmcnt(0)\n\ts_barrier" ::: "memory");
    }
    const int cur = s % 3;
    bf16x8 af[4], bfr[4];
#pragma unroll
    for (int m = 0; m < 4; ++m) {
      const int r = wr * 64 + m * 16 + lr;
      const int slot = lks ^ (r & 3);
      af[m] = *(const bf16x8*)(&As[cur][r * 32 + slot * 8]);
    }
#pragma unroll
    for (int n = 0; n < 4; ++n) {
      const int r = wc * 64 + n * 16 + lr;
      const int slot = lks ^ (r & 3);
      bfr[n] = *(const bf16x8*)(&Bs[cur][r * 32 + slot * 8]);
    }
#pragma unroll
    for (int m = 0; m < 4; ++m)
#pragma unroll
      for (int n = 0; n < 4; ++n)
        acc[m][n] = __builtin_amdgcn_mfma_f32_16x16x32_bf16(af[m], bfr[n], acc[m][n], 0, 0, 0);
    // Guard ring-slot reuse: next iteration's STAGE overwrites buf (s+3)%3 == cur.
    // "memory" clobber keeps ds_reads (and their lgkmcnt waits) above this point.
    asm volatile("s_barrier" ::: "memory");
  }

  // epilogue: D row=(l>>4)*4+reg (M), col=l&15 (N)
#pragma unroll
  for (int m = 0; m < 4; ++m)
#pragma unroll
    for (int n = 0; n < 4; ++n)
#pragma unroll
      for (int r = 0; r < 4; ++r) {
        const int row = tm * 128 + wr * 64 + m * 16 + (l >> 4) * 4 + r;
        const int col = tn * 128 + wc * 64 + n * 16 + lr;
        if (OBF) {
          ((unsigned short*)Cv)[bz * strideC + (size_t)row * LDCv + col] =
              f2bf(acc[m][n][r] * scale);
        } else {
          ((float*)Cv)[bz * strideC + (size_t)row * LDCv + col] = acc[m][n][r] * scale;
        }
      }
}

// ---------------- K3: v f32 -> bf16 (no transpose)
__global__ __launch_bounds__(256) void convert_v(
    const float* __restrict__ v, unsigned short* __restrict__ vB) {
  const size_t i8 = (size_t)blockIdx.x * 256 + threadIdx.x;
  const float4 a = *(const float4*)(v + i8 * 8);
  const float4 b = *(const float4*)(v + i8 * 8 + 4);
  bf16x8 o;
  o[0] = (short)f2bf(a.x); o[1] = (short)f2bf(a.y);
  o[2] = (short)f2bf(a.z); o[3] = (short)f2bf(a.w);
  o[4] = (short)f2bf(b.x); o[5] = (short)f2bf(b.y);
  o[6] = (short)f2bf(b.z); o[7] = (short)f2bf(b.w);
  *(bf16x8*)(vB + i8 * 8) = o;
}

// ---------------- K2: in-place softmax over b (16 values) at each (j,i)
__global__ __launch_bounds__(256) void softmax_b(unsigned short* __restrict__ SP) {
  const size_t off = ((size_t)blockIdx.x * 256 + threadIdx.x) * 8;
  bf16x8 s[BN];
#pragma unroll
  for (int b = 0; b < BN; ++b)
    s[b] = *(const bf16x8*)(SP + (size_t)b * (LN * LN) + off);
#pragma unroll
  for (int e = 0; e < 8; ++e) {
    float vv[BN];
#pragma unroll
    for (int b = 0; b < BN; ++b) vv[b] = bf2f((unsigned short)s[b][e]);
    float m = vv[0];
#pragma unroll
    for (int b = 1; b < BN; ++b) m = fmaxf(m, vv[b]);
    float tt[BN], sum = 0.f;
#pragma unroll
    for (int b = 0; b < BN; ++b) { tt[b] = __expf(vv[b] - m); sum += tt[b]; }
    const float inv = 1.f / sum;
#pragma unroll
    for (int b = 0; b < BN; ++b) s[b][e] = (short)f2bf(tt[b] * inv);
  }
#pragma unroll
  for (int b = 0; b < BN; ++b)
    *(bf16x8*)(SP + (size_t)b * (LN * LN) + off) = s[b];
}

extern "C" void kernel_launch(void* const* d_in, const int* in_sizes, int n_in,
                              void* d_out, int out_size, void* d_ws, size_t ws_size,
                              hipStream_t stream) {
  const float* q = (const float*)d_in[0];
  const float* k = (const float*)d_in[1];
  const float* v = (const float*)d_in[2];
  float* out = (float*)d_out;

  unsigned short* qT = (unsigned short*)d_ws;            // 16 MiB
  unsigned short* kT = qT + (size_t)BN * LN * CC;        // 16 MiB
  unsigned short* SP = kT + (size_t)BN * LN * CC;        // 32 MiB (S' then P)
  unsigned short* vB = qT;                               // overlay (qT dead after K1)

  transpose_convert<<<dim3(LN / 32, CC / 32, BN * 2), 256, 0, stream>>>(q, k, qT, kT);
  // K1: S' = (qT . kT^T)/32, bf16. M=N=1024, K=512.
  gemm_glds<512, 512, 512, 1024, true><<<dim3(8, 8, BN), 256, 0, stream>>>(
      qT, kT, (void*)SP, 0.03125f,
      (size_t)LN * CC, (size_t)LN * CC, (size_t)LN * LN);
  convert_v<<<dim3((BN * CC * LN) / 8 / 256), 256, 0, stream>>>(v, vB);
  softmax_b<<<dim3((LN * LN) / 8 / 256), 256, 0, stream>>>(SP);
  // K4: out = vB . P^T, f32. M=512, N=1024, K=1024.
  gemm_glds<1024, 1024, 1024, 1024, false><<<dim3(8, 4, BN), 256, 0, stream>>>(
      vB, SP, (void*)out, 1.0f,
      (size_t)CC * LN, (size_t)LN * LN, (size_t)CC * LN);
}

// Round 10
// 95.406 us; speedup vs baseline: 1.1069x; 1.1069x over previous
//
#include <hip/hip_runtime.h>
#include <hip/hip_bf16.h>

// B=16, C=512, L=1024.
// score[b,i,j] = sum_c k[b,c,i]*q[b,c,j] / 32 ; P = softmax over b (axis=0!)
// out[b,c,j] = sum_i v[b,c,i]*P[b,i,j]
// Pipeline (all bf16 MFMA, fp32 accum):
//   K0 transpose_convert: q,k f32 [b][c][l] -> qT,kT bf16 [b][l][c]
//   K1 gemm_glds: S'[b][j][i] = (qT . kT^T)/32, bf16   (batched 1024x1024x512)
//   K3 convert_v: v f32 -> vB bf16 [b][c][i]  (overlays qT, dead after K1)
//   K2 softmax_b: in-place softmax over b (16 per (j,i)) on S'
//   K4 gemm_glds: out[b][c][j] = vB . P^T, f32         (batched 512x1024x1024)
// GEMM: 128x128 tile, BK=32 double-buffered (32 KiB LDS -> 5 blocks/CU),
// global_load_lds w=16 into linear LDS.
// Swizzle (fixed this round): rows are 64B, row r starts at bank 16*(r&1), so
// the slot XOR must use row bits [2:1]: phys slot = logical ^ ((r>>1)&3).
// Applied BOTH sides (rule 21): global source column + ds_read address.
// XCD remap (T1): chunk of nwg/8 consecutive work-ids per XCD; a 128-block
// chunk = 2 full batches = 4MB of A+B panels = one XCD's L2.

#define LN 1024
#define CC 512
#define BN 16

typedef __attribute__((ext_vector_type(8))) short bf16x8;
typedef __attribute__((ext_vector_type(4))) float f32x4;

static __device__ __forceinline__ unsigned short f2bf(float x) {
  union { float f; unsigned u; } un; un.f = x;
  unsigned r = un.u + 0x7fffu + ((un.u >> 16) & 1u);   // RNE
  return (unsigned short)(r >> 16);
}
static __device__ __forceinline__ float bf2f(unsigned short h) {
  union { unsigned u; float f; } un; un.u = ((unsigned)h) << 16; return un.f;
}

// ---------------- K0: transpose-convert q,k (f32 [b][c][l]) -> bf16 [b][l][c]
__global__ __launch_bounds__(256) void transpose_convert(
    const float* __restrict__ q, const float* __restrict__ k,
    unsigned short* __restrict__ qT, unsigned short* __restrict__ kT) {
  __shared__ float tile[32][33];
  const int b   = blockIdx.z >> 1;
  const int mat = blockIdx.z & 1;
  const float* src = mat ? k : q;
  unsigned short* dst = mat ? kT : qT;
  const int l0 = blockIdx.x * 32, c0 = blockIdx.y * 32;
  const int t = threadIdx.x;
  const int ll = t & 31, cbase = t >> 5;
  const float* sp = src + ((size_t)b * CC + c0) * LN + l0;
#pragma unroll
  for (int r = 0; r < 4; ++r) {
    int cc = cbase + r * 8;
    tile[cc][ll] = sp[(size_t)cc * LN + ll];
  }
  __syncthreads();
  const int co = t & 31, lbase = t >> 5;
  unsigned short* dp = dst + ((size_t)b * LN + l0) * CC + c0;
#pragma unroll
  for (int r = 0; r < 4; ++r) {
    int lo = lbase + r * 8;
    dp[(size_t)lo * CC + co] = f2bf(tile[co][lo]);
  }
}

// ---------------- batched GEMM, both operands K-contiguous:
// C[row][col] = scale * sum_k A[row][k] * B[col][k]
// 128x128 tile, BK=32 (64B rows), dbuf, 4 waves 2x2, 4x4 frags of 16x16x32.
template<int KD, int LDAv, int LDBv, int LDCv, bool OBF, int NTN, int NTM, int NB>
__global__ __launch_bounds__(256, 5) void gemm_glds(
    const unsigned short* __restrict__ A, const unsigned short* __restrict__ B,
    void* __restrict__ Cv, float scale,
    size_t strideA, size_t strideB, size_t strideC) {
  __shared__ unsigned short As[2][128 * 32];   // 2 x 8 KiB
  __shared__ unsigned short Bs[2][128 * 32];   // 2 x 8 KiB  (total 32 KiB)

  // T1: bijective XCD-chunk remap. HW: XCD = flat_id % 8 (heuristic).
  constexpr int nwg = NTN * NTM * NB;          // 1024 (K1) / 512 (K4), %8==0
  const int f = blockIdx.x + NTN * (blockIdx.y + NTM * blockIdx.z);
  const int wid = (f & 7) * (nwg >> 3) + (f >> 3);
  const int tn = wid % NTN;
  const int tm = (wid / NTN) % NTM;
  const int bz = wid / (NTN * NTM);

  const unsigned short* Ab = A + (size_t)bz * strideA;
  const unsigned short* Bb = B + (size_t)bz * strideB;
  const int t = threadIdx.x, w = t >> 6, l = t & 63;
  const int wr = w >> 1, wc = w & 1;
  const int lr = l & 15, lks = l >> 4;         // logical k-slot 0..3 (8 shorts)

  f32x4 acc[4][4];
#pragma unroll
  for (int m = 0; m < 4; ++m)
#pragma unroll
    for (int n = 0; n < 4; ++n) acc[m][n] = (f32x4){0.f, 0.f, 0.f, 0.f};

  // staging: thread t covers (row = qq*64 + t/4, phys slot = t&3); LDS dest is
  // linear (glds requires it); global source column carries the inverse swizzle.
  const int srow = t >> 2;        // 0..63
  const int sslot = t & 3;

  auto STAGE = [&](int buf, int step) {   // 4 glds instructions
    const int c0 = step * 32;
#pragma unroll
    for (int qq = 0; qq < 2; ++qq) {
      const int row = qq * 64 + srow;
      const unsigned short* ga =
          Ab + (size_t)(tm * 128 + row) * LDAv + c0 + ((sslot ^ ((row >> 1) & 3)) * 8);
      __builtin_amdgcn_global_load_lds(
          (const __attribute__((address_space(1))) void*)ga,
          (__attribute__((address_space(3))) void*)&As[buf][qq * 2048 + t * 8],
          16, 0, 0);
    }
#pragma unroll
    for (int qq = 0; qq < 2; ++qq) {
      const int row = qq * 64 + srow;
      const unsigned short* gb =
          Bb + (size_t)(tn * 128 + row) * LDBv + c0 + ((sslot ^ ((row >> 1) & 3)) * 8);
      __builtin_amdgcn_global_load_lds(
          (const __attribute__((address_space(1))) void*)gb,
          (__attribute__((address_space(3))) void*)&Bs[buf][qq * 2048 + t * 8],
          16, 0, 0);
    }
  };

  STAGE(0, 0);
  __syncthreads();   // drains vmcnt(0): buf0 staged

  const int NSTEP = KD / 32;
  int cur = 0;
#pragma unroll 1
  for (int step = 0; step < NSTEP; ++step) {
    if (step + 1 < NSTEP) STAGE(cur ^ 1, step + 1);
    bf16x8 af[4], bfr[4];
#pragma unroll
    for (int m = 0; m < 4; ++m) {
      const int r = wr * 64 + m * 16 + lr;
      const int slot = lks ^ ((r >> 1) & 3);
      af[m] = *(const bf16x8*)(&As[cur][r * 32 + slot * 8]);
    }
#pragma unroll
    for (int n = 0; n < 4; ++n) {
      const int r = wc * 64 + n * 16 + lr;
      const int slot = lks ^ ((r >> 1) & 3);
      bfr[n] = *(const bf16x8*)(&Bs[cur][r * 32 + slot * 8]);
    }
#pragma unroll
    for (int m = 0; m < 4; ++m)
#pragma unroll
      for (int n = 0; n < 4; ++n)
        acc[m][n] = __builtin_amdgcn_mfma_f32_16x16x32_bf16(af[m], bfr[n], acc[m][n], 0, 0, 0);
    __syncthreads();   // drains next-tile stage + guards buffer reuse
    cur ^= 1;
  }

  // epilogue: D row=(l>>4)*4+reg (M), col=l&15 (N)
#pragma unroll
  for (int m = 0; m < 4; ++m)
#pragma unroll
    for (int n = 0; n < 4; ++n)
#pragma unroll
      for (int r = 0; r < 4; ++r) {
        const int row = tm * 128 + wr * 64 + m * 16 + (l >> 4) * 4 + r;
        const int col = tn * 128 + wc * 64 + n * 16 + lr;
        if (OBF) {
          ((unsigned short*)Cv)[bz * strideC + (size_t)row * LDCv + col] =
              f2bf(acc[m][n][r] * scale);
        } else {
          ((float*)Cv)[bz * strideC + (size_t)row * LDCv + col] = acc[m][n][r] * scale;
        }
      }
}

// ---------------- K3: v f32 -> bf16 (no transpose)
__global__ __launch_bounds__(256) void convert_v(
    const float* __restrict__ v, unsigned short* __restrict__ vB) {
  const size_t i8 = (size_t)blockIdx.x * 256 + threadIdx.x;
  const float4 a = *(const float4*)(v + i8 * 8);
  const float4 b = *(const float4*)(v + i8 * 8 + 4);
  bf16x8 o;
  o[0] = (short)f2bf(a.x); o[1] = (short)f2bf(a.y);
  o[2] = (short)f2bf(a.z); o[3] = (short)f2bf(a.w);
  o[4] = (short)f2bf(b.x); o[5] = (short)f2bf(b.y);
  o[6] = (short)f2bf(b.z); o[7] = (short)f2bf(b.w);
  *(bf16x8*)(vB + i8 * 8) = o;
}

// ---------------- K2: in-place softmax over b (16 values) at each (j,i)
__global__ __launch_bounds__(256) void softmax_b(unsigned short* __restrict__ SP) {
  const size_t off = ((size_t)blockIdx.x * 256 + threadIdx.x) * 8;
  bf16x8 s[BN];
#pragma unroll
  for (int b = 0; b < BN; ++b)
    s[b] = *(const bf16x8*)(SP + (size_t)b * (LN * LN) + off);
#pragma unroll
  for (int e = 0; e < 8; ++e) {
    float vv[BN];
#pragma unroll
    for (int b = 0; b < BN; ++b) vv[b] = bf2f((unsigned short)s[b][e]);
    float m = vv[0];
#pragma unroll
    for (int b = 1; b < BN; ++b) m = fmaxf(m, vv[b]);
    float tt[BN], sum = 0.f;
#pragma unroll
    for (int b = 0; b < BN; ++b) { tt[b] = __expf(vv[b] - m); sum += tt[b]; }
    const float inv = 1.f / sum;
#pragma unroll
    for (int b = 0; b < BN; ++b) s[b][e] = (short)f2bf(tt[b] * inv);
  }
#pragma unroll
  for (int b = 0; b < BN; ++b)
    *(bf16x8*)(SP + (size_t)b * (LN * LN) + off) = s[b];
}

extern "C" void kernel_launch(void* const* d_in, const int* in_sizes, int n_in,
                              void* d_out, int out_size, void* d_ws, size_t ws_size,
                              hipStream_t stream) {
  const float* q = (const float*)d_in[0];
  const float* k = (const float*)d_in[1];
  const float* v = (const float*)d_in[2];
  float* out = (float*)d_out;

  unsigned short* qT = (unsigned short*)d_ws;            // 16 MiB
  unsigned short* kT = qT + (size_t)BN * LN * CC;        // 16 MiB
  unsigned short* SP = kT + (size_t)BN * LN * CC;        // 32 MiB (S' then P)
  unsigned short* vB = qT;                               // overlay (qT dead after K1)

  transpose_convert<<<dim3(LN / 32, CC / 32, BN * 2), 256, 0, stream>>>(q, k, qT, kT);
  // K1: S' = (qT . kT^T)/32, bf16. M=N=1024, K=512.
  gemm_glds<512, 512, 512, 1024, true, 8, 8, BN><<<dim3(8, 8, BN), 256, 0, stream>>>(
      qT, kT, (void*)SP, 0.03125f,
      (size_t)LN * CC, (size_t)LN * CC, (size_t)LN * LN);
  convert_v<<<dim3((BN * CC * LN) / 8 / 256), 256, 0, stream>>>(v, vB);
  softmax_b<<<dim3((LN * LN) / 8 / 256), 256, 0, stream>>>(SP);
  // K4: out = vB . P^T, f32. M=512, N=1024, K=1024.
  gemm_glds<1024, 1024, 1024, 1024, false, 8, 4, BN><<<dim3(8, 4, BN), 256, 0, stream>>>(
      vB, SP, (void*)out, 1.0f,
      (size_t)CC * LN, (size_t)LN * LN, (size_t)CC * LN);
}

// Round 11
// 92.827 us; speedup vs baseline: 1.1377x; 1.0278x over previous
//
#include <hip/hip_runtime.h>
#include <hip/hip_bf16.h>

// B=16, C=512, L=1024.
// score[b,i,j] = sum_c k[b,c,i]*q[b,c,j] / 32 ; P = softmax over b (axis=0!)
// out[b,c,j] = sum_i v[b,c,i]*P[b,i,j]
// Pipeline:
//   K0 transpose_convert: q,k f32 [b][c][l] -> qT,kT bf16 [b][l][c]
//   K1 gemm_8ph: S'[b][j][i] = (qT . kT^T)/32, bf16   (256^2 8-phase template)
//   K3 convert_v: v f32 -> vB bf16
//   K2 softmax_b: in-place softmax over b on S'
//   K4 gemm_glds: out[b][c][j] = vB . P^T, f32        (128^2 2-phase, R10)
//
// K1 = 256x256 tile, BK=64, 512 thr (8 waves 2Mx4N, per-wave 128x64), LDS
// 128 KiB dbuf. 4 phases per K-tile: {ds_read subtile; stage 1 half;
// s_barrier; [lgkm by compiler]; setprio(1); 16 MFMA; setprio(0); s_barrier}.
// Stage order: A0,A1(T+1) at ph0,1 (other dbuf, safe); B0,B1(T+2) at ph2,3
// (current dbuf -- tile T's B reads fully drained by ph1's lgkm+barrier).
// Counted vmcnt(4)+barrier once per tile at ph3 => tile T+1 fully staged.
// Swizzle: 16B-unit ^= (row&7), applied to glds SOURCE and ds_read (rule 21).

#define LN 1024
#define CC 512
#define BN 16

typedef __attribute__((ext_vector_type(8))) short bf16x8;
typedef __attribute__((ext_vector_type(4))) float f32x4;

static __device__ __forceinline__ unsigned short f2bf(float x) {
  union { float f; unsigned u; } un; un.f = x;
  unsigned r = un.u + 0x7fffu + ((un.u >> 16) & 1u);   // RNE
  return (unsigned short)(r >> 16);
}
static __device__ __forceinline__ float bf2f(unsigned short h) {
  union { unsigned u; float f; } un; un.u = ((unsigned)h) << 16; return un.f;
}

// ---------------- K0: transpose-convert q,k (f32 [b][c][l]) -> bf16 [b][l][c]
__global__ __launch_bounds__(256) void transpose_convert(
    const float* __restrict__ q, const float* __restrict__ k,
    unsigned short* __restrict__ qT, unsigned short* __restrict__ kT) {
  __shared__ float tile[32][33];
  const int b   = blockIdx.z >> 1;
  const int mat = blockIdx.z & 1;
  const float* src = mat ? k : q;
  unsigned short* dst = mat ? kT : qT;
  const int l0 = blockIdx.x * 32, c0 = blockIdx.y * 32;
  const int t = threadIdx.x;
  const int ll = t & 31, cbase = t >> 5;
  const float* sp = src + ((size_t)b * CC + c0) * LN + l0;
#pragma unroll
  for (int r = 0; r < 4; ++r) {
    int cc = cbase + r * 8;
    tile[cc][ll] = sp[(size_t)cc * LN + ll];
  }
  __syncthreads();
  const int co = t & 31, lbase = t >> 5;
  unsigned short* dp = dst + ((size_t)b * LN + l0) * CC + c0;
#pragma unroll
  for (int r = 0; r < 4; ++r) {
    int lo = lbase + r * 8;
    dp[(size_t)lo * CC + co] = f2bf(tile[co][lo]);
  }
}

// ---------------- K1: 256^2 8-phase batched GEMM (both operands K-contig)
// C[row][col] = scale * sum_k A[row][k]*B[col][k]
template<int KD, int LDAv, int LDBv, int LDCv, bool OBF, int NTN, int NTM, int NB>
__global__ __launch_bounds__(512, 2) void gemm_8ph(
    const unsigned short* __restrict__ A, const unsigned short* __restrict__ B,
    void* __restrict__ Cv, float scale,
    size_t strideA, size_t strideB, size_t strideC) {
  __shared__ unsigned short As[2][2][128 * 64];   // [dbuf][half][row*64 + unit*8]
  __shared__ unsigned short Bs[2][2][128 * 64];   // 64 KiB + 64 KiB

  constexpr int nwg = NTN * NTM * NB;             // %8 == 0
  const int f = blockIdx.x + NTN * (blockIdx.y + NTM * blockIdx.z);
  const int wid = (f & 7) * (nwg >> 3) + (f >> 3);
  const int tn = wid % NTN;
  const int tm = (wid / NTN) % NTM;
  const int bz = wid / (NTN * NTM);

  const unsigned short* Ab = A + (size_t)bz * strideA;
  const unsigned short* Bb = B + (size_t)bz * strideB;

  const int t = threadIdx.x;
  const int w = t >> 6, l = t & 63;
  const int wr = w >> 2;        // 0..1 : M-half  (= A LDS half index)
  const int wc = w & 3;         // 0..3 : N-quarter (B half = wc>>1)
  const int lr = l & 15, lks = l >> 4;

  f32x4 acc[8][4];
#pragma unroll
  for (int m = 0; m < 8; ++m)
#pragma unroll
    for (int n = 0; n < 4; ++n) acc[m][n] = (f32x4){0.f, 0.f, 0.f, 0.f};

  const int NSTEP = KD / 64;

  auto SA = [&](int tile, int h) {   // stage A half h of K-tile 'tile' (2 glds)
    const int buf = tile & 1, c0 = tile * 64;
#pragma unroll
    for (int j = 0; j < 2; ++j) {
      const int s = j * 512 + t, r = s >> 3, pu = s & 7;
      const unsigned short* g =
          Ab + (size_t)(tm * 256 + h * 128 + r) * LDAv + c0 + ((pu ^ (r & 7)) * 8);
      __builtin_amdgcn_global_load_lds(
          (const __attribute__((address_space(1))) void*)g,
          (__attribute__((address_space(3))) void*)&As[buf][h][s * 8], 16, 0, 0);
    }
  };
  auto SB = [&](int tile, int h) {
    const int buf = tile & 1, c0 = tile * 64;
#pragma unroll
    for (int j = 0; j < 2; ++j) {
      const int s = j * 512 + t, r = s >> 3, pu = s & 7;
      const unsigned short* g =
          Bb + (size_t)(tn * 256 + h * 128 + r) * LDBv + c0 + ((pu ^ (r & 7)) * 8);
      __builtin_amdgcn_global_load_lds(
          (const __attribute__((address_space(1))) void*)g,
          (__attribute__((address_space(3))) void*)&Bs[buf][h][s * 8], 16, 0, 0);
    }
  };
  auto LA = [&](int buf, int rloc, int kk) -> bf16x8 {
    return *(const bf16x8*)(&As[buf][wr][rloc * 64 + (((kk * 4 + lks) ^ (rloc & 7)) * 8)]);
  };
  auto LB = [&](int buf, int rloc, int kk) -> bf16x8 {
    return *(const bf16x8*)(&Bs[buf][wc >> 1][rloc * 64 + (((kk * 4 + lks) ^ (rloc & 7)) * 8)]);
  };

  // prologue: tile0 complete + B halves of tile1; wait leaves t1's B in flight
  SB(0, 0); SB(0, 1); SA(0, 0); SA(0, 1);
  if (NSTEP > 1) { SB(1, 0); SB(1, 1); }
  asm volatile("s_waitcnt vmcnt(4)\n\ts_barrier" ::: "memory");

  bf16x8 a[4][2], b[4][2];
  const int brow = (wc & 1) * 64;   // wave's base row within its B half

#pragma unroll 1
  for (int T = 0; T < NSTEP; ++T) {
    const int buf = T & 1;
    // ---- phase 0: read a(m0..3) + b(n0..1); stage A0(T+1); MFMA quad (lo,lo)
#pragma unroll
    for (int m = 0; m < 4; ++m) {
      a[m][0] = LA(buf, m * 16 + lr, 0);
      a[m][1] = LA(buf, m * 16 + lr, 1);
    }
#pragma unroll
    for (int n = 0; n < 2; ++n) {
      b[n][0] = LB(buf, brow + n * 16 + lr, 0);
      b[n][1] = LB(buf, brow + n * 16 + lr, 1);
    }
    if (T + 1 < NSTEP) SA(T + 1, 0);
    asm volatile("s_barrier" ::: "memory");
    __builtin_amdgcn_s_setprio(1);
#pragma unroll
    for (int m = 0; m < 4; ++m)
#pragma unroll
      for (int n = 0; n < 2; ++n) {
        acc[m][n] = __builtin_amdgcn_mfma_f32_16x16x32_bf16(a[m][0], b[n][0], acc[m][n], 0, 0, 0);
        acc[m][n] = __builtin_amdgcn_mfma_f32_16x16x32_bf16(a[m][1], b[n][1], acc[m][n], 0, 0, 0);
      }
    __builtin_amdgcn_s_setprio(0);
    asm volatile("s_barrier" ::: "memory");
    // ---- phase 1: read b(n2..3); stage A1(T+1); MFMA quad (lo,hi)
#pragma unroll
    for (int n = 2; n < 4; ++n) {
      b[n][0] = LB(buf, brow + n * 16 + lr, 0);
      b[n][1] = LB(buf, brow + n * 16 + lr, 1);
    }
    if (T + 1 < NSTEP) SA(T + 1, 1);
    asm volatile("s_barrier" ::: "memory");
    __builtin_amdgcn_s_setprio(1);
#pragma unroll
    for (int m = 0; m < 4; ++m)
#pragma unroll
      for (int n = 2; n < 4; ++n) {
        acc[m][n] = __builtin_amdgcn_mfma_f32_16x16x32_bf16(a[m][0], b[n][0], acc[m][n], 0, 0, 0);
        acc[m][n] = __builtin_amdgcn_mfma_f32_16x16x32_bf16(a[m][1], b[n][1], acc[m][n], 0, 0, 0);
      }
    __builtin_amdgcn_s_setprio(0);
    asm volatile("s_barrier" ::: "memory");
    // ---- phase 2: read a(m4..7); stage B0(T+2) (tile T's B reads all drained
    //      by phase-1 lgkm+barrier -> strict-safe); MFMA quad (hi,lo)
#pragma unroll
    for (int m = 0; m < 4; ++m) {
      a[m][0] = LA(buf, 64 + m * 16 + lr, 0);
      a[m][1] = LA(buf, 64 + m * 16 + lr, 1);
    }
    if (T + 2 < NSTEP) SB(T + 2, 0);
    asm volatile("s_barrier" ::: "memory");
    __builtin_amdgcn_s_setprio(1);
#pragma unroll
    for (int m = 0; m < 4; ++m)
#pragma unroll
      for (int n = 0; n < 2; ++n) {
        acc[m + 4][n] = __builtin_amdgcn_mfma_f32_16x16x32_bf16(a[m][0], b[n][0], acc[m + 4][n], 0, 0, 0);
        acc[m + 4][n] = __builtin_amdgcn_mfma_f32_16x16x32_bf16(a[m][1], b[n][1], acc[m + 4][n], 0, 0, 0);
      }
    __builtin_amdgcn_s_setprio(0);
    asm volatile("s_barrier" ::: "memory");
    // ---- phase 3: stage B1(T+2); counted vmcnt (tile T+1 fully staged);
    //      MFMA quad (hi,hi)
    if (T + 2 < NSTEP) SB(T + 2, 1);
    if (T < NSTEP - 2) {
      asm volatile("s_waitcnt vmcnt(4)" ::: "memory");
    } else if (T == NSTEP - 2) {
      asm volatile("s_waitcnt vmcnt(0)" ::: "memory");
    }
    asm volatile("s_barrier" ::: "memory");
    __builtin_amdgcn_s_setprio(1);
#pragma unroll
    for (int m = 0; m < 4; ++m)
#pragma unroll
      for (int n = 2; n < 4; ++n) {
        acc[m + 4][n] = __builtin_amdgcn_mfma_f32_16x16x32_bf16(a[m][0], b[n][0], acc[m + 4][n], 0, 0, 0);
        acc[m + 4][n] = __builtin_amdgcn_mfma_f32_16x16x32_bf16(a[m][1], b[n][1], acc[m + 4][n], 0, 0, 0);
      }
    __builtin_amdgcn_s_setprio(0);
    asm volatile("s_barrier" ::: "memory");
  }

  // epilogue: D row=(l>>4)*4+reg (M side), col=l&15 (N side)
#pragma unroll
  for (int m = 0; m < 8; ++m)
#pragma unroll
    for (int n = 0; n < 4; ++n)
#pragma unroll
      for (int r = 0; r < 4; ++r) {
        const int row = tm * 256 + wr * 128 + m * 16 + (l >> 4) * 4 + r;
        const int col = tn * 256 + wc * 64 + n * 16 + lr;
        if (OBF) {
          ((unsigned short*)Cv)[bz * strideC + (size_t)row * LDCv + col] =
              f2bf(acc[m][n][r] * scale);
        } else {
          ((float*)Cv)[bz * strideC + (size_t)row * LDCv + col] = acc[m][n][r] * scale;
        }
      }
}

// ---------------- K4: 128^2 2-phase batched GEMM (R10, unchanged)
template<int KD, int LDAv, int LDBv, int LDCv, bool OBF, int NTN, int NTM, int NB>
__global__ __launch_bounds__(256, 5) void gemm_glds(
    const unsigned short* __restrict__ A, const unsigned short* __restrict__ B,
    void* __restrict__ Cv, float scale,
    size_t strideA, size_t strideB, size_t strideC) {
  __shared__ unsigned short As[2][128 * 32];
  __shared__ unsigned short Bs[2][128 * 32];

  constexpr int nwg = NTN * NTM * NB;
  const int f = blockIdx.x + NTN * (blockIdx.y + NTM * blockIdx.z);
  const int wid = (f & 7) * (nwg >> 3) + (f >> 3);
  const int tn = wid % NTN;
  const int tm = (wid / NTN) % NTM;
  const int bz = wid / (NTN * NTM);

  const unsigned short* Ab = A + (size_t)bz * strideA;
  const unsigned short* Bb = B + (size_t)bz * strideB;
  const int t = threadIdx.x, w = t >> 6, l = t & 63;
  const int wr = w >> 1, wc = w & 1;
  const int lr = l & 15, lks = l >> 4;

  f32x4 acc[4][4];
#pragma unroll
  for (int m = 0; m < 4; ++m)
#pragma unroll
    for (int n = 0; n < 4; ++n) acc[m][n] = (f32x4){0.f, 0.f, 0.f, 0.f};

  const int srow = t >> 2;
  const int sslot = t & 3;

  auto STAGE = [&](int buf, int step) {
    const int c0 = step * 32;
#pragma unroll
    for (int qq = 0; qq < 2; ++qq) {
      const int row = qq * 64 + srow;
      const unsigned short* ga =
          Ab + (size_t)(tm * 128 + row) * LDAv + c0 + ((sslot ^ ((row >> 1) & 3)) * 8);
      __builtin_amdgcn_global_load_lds(
          (const __attribute__((address_space(1))) void*)ga,
          (__attribute__((address_space(3))) void*)&As[buf][qq * 2048 + t * 8],
          16, 0, 0);
    }
#pragma unroll
    for (int qq = 0; qq < 2; ++qq) {
      const int row = qq * 64 + srow;
      const unsigned short* gb =
          Bb + (size_t)(tn * 128 + row) * LDBv + c0 + ((sslot ^ ((row >> 1) & 3)) * 8);
      __builtin_amdgcn_global_load_lds(
          (const __attribute__((address_space(1))) void*)gb,
          (__attribute__((address_space(3))) void*)&Bs[buf][qq * 2048 + t * 8],
          16, 0, 0);
    }
  };

  STAGE(0, 0);
  __syncthreads();

  const int NSTEP = KD / 32;
  int cur = 0;
#pragma unroll 1
  for (int step = 0; step < NSTEP; ++step) {
    if (step + 1 < NSTEP) STAGE(cur ^ 1, step + 1);
    bf16x8 af[4], bfr[4];
#pragma unroll
    for (int m = 0; m < 4; ++m) {
      const int r = wr * 64 + m * 16 + lr;
      const int slot = lks ^ ((r >> 1) & 3);
      af[m] = *(const bf16x8*)(&As[cur][r * 32 + slot * 8]);
    }
#pragma unroll
    for (int n = 0; n < 4; ++n) {
      const int r = wc * 64 + n * 16 + lr;
      const int slot = lks ^ ((r >> 1) & 3);
      bfr[n] = *(const bf16x8*)(&Bs[cur][r * 32 + slot * 8]);
    }
#pragma unroll
    for (int m = 0; m < 4; ++m)
#pragma unroll
      for (int n = 0; n < 4; ++n)
        acc[m][n] = __builtin_amdgcn_mfma_f32_16x16x32_bf16(af[m], bfr[n], acc[m][n], 0, 0, 0);
    __syncthreads();
    cur ^= 1;
  }

#pragma unroll
  for (int m = 0; m < 4; ++m)
#pragma unroll
    for (int n = 0; n < 4; ++n)
#pragma unroll
      for (int r = 0; r < 4; ++r) {
        const int row = tm * 128 + wr * 64 + m * 16 + (l >> 4) * 4 + r;
        const int col = tn * 128 + wc * 64 + n * 16 + lr;
        if (OBF) {
          ((unsigned short*)Cv)[bz * strideC + (size_t)row * LDCv + col] =
              f2bf(acc[m][n][r] * scale);
        } else {
          ((float*)Cv)[bz * strideC + (size_t)row * LDCv + col] = acc[m][n][r] * scale;
        }
      }
}

// ---------------- K3: v f32 -> bf16 (no transpose)
__global__ __launch_bounds__(256) void convert_v(
    const float* __restrict__ v, unsigned short* __restrict__ vB) {
  const size_t i8 = (size_t)blockIdx.x * 256 + threadIdx.x;
  const float4 a = *(const float4*)(v + i8 * 8);
  const float4 b = *(const float4*)(v + i8 * 8 + 4);
  bf16x8 o;
  o[0] = (short)f2bf(a.x); o[1] = (short)f2bf(a.y);
  o[2] = (short)f2bf(a.z); o[3] = (short)f2bf(a.w);
  o[4] = (short)f2bf(b.x); o[5] = (short)f2bf(b.y);
  o[6] = (short)f2bf(b.z); o[7] = (short)f2bf(b.w);
  *(bf16x8*)(vB + i8 * 8) = o;
}

// ---------------- K2: in-place softmax over b (16 values) at each (j,i)
__global__ __launch_bounds__(256) void softmax_b(unsigned short* __restrict__ SP) {
  const size_t off = ((size_t)blockIdx.x * 256 + threadIdx.x) * 8;
  bf16x8 s[BN];
#pragma unroll
  for (int b = 0; b < BN; ++b)
    s[b] = *(const bf16x8*)(SP + (size_t)b * (LN * LN) + off);
#pragma unroll
  for (int e = 0; e < 8; ++e) {
    float vv[BN];
#pragma unroll
    for (int b = 0; b < BN; ++b) vv[b] = bf2f((unsigned short)s[b][e]);
    float m = vv[0];
#pragma unroll
    for (int b = 1; b < BN; ++b) m = fmaxf(m, vv[b]);
    float tt[BN], sum = 0.f;
#pragma unroll
    for (int b = 0; b < BN; ++b) { tt[b] = __expf(vv[b] - m); sum += tt[b]; }
    const float inv = 1.f / sum;
#pragma unroll
    for (int b = 0; b < BN; ++b) s[b][e] = (short)f2bf(tt[b] * inv);
  }
#pragma unroll
  for (int b = 0; b < BN; ++b)
    *(bf16x8*)(SP + (size_t)b * (LN * LN) + off) = s[b];
}

extern "C" void kernel_launch(void* const* d_in, const int* in_sizes, int n_in,
                              void* d_out, int out_size, void* d_ws, size_t ws_size,
                              hipStream_t stream) {
  const float* q = (const float*)d_in[0];
  const float* k = (const float*)d_in[1];
  const float* v = (const float*)d_in[2];
  float* out = (float*)d_out;

  unsigned short* qT = (unsigned short*)d_ws;            // 16 MiB
  unsigned short* kT = qT + (size_t)BN * LN * CC;        // 16 MiB
  unsigned short* SP = kT + (size_t)BN * LN * CC;        // 32 MiB (S' then P)
  unsigned short* vB = qT;                               // overlay (qT dead after K1)

  transpose_convert<<<dim3(LN / 32, CC / 32, BN * 2), 256, 0, stream>>>(q, k, qT, kT);
  // K1: S' = (qT . kT^T)/32, bf16. M=N=1024, K=512 -> 4x4x16 blocks of 256^2.
  gemm_8ph<512, 512, 512, 1024, true, 4, 4, BN><<<dim3(4, 4, BN), 512, 0, stream>>>(
      qT, kT, (void*)SP, 0.03125f,
      (size_t)LN * CC, (size_t)LN * CC, (size_t)LN * LN);
  convert_v<<<dim3((BN * CC * LN) / 8 / 256), 256, 0, stream>>>(v, vB);
  softmax_b<<<dim3((LN * LN) / 8 / 256), 256, 0, stream>>>(SP);
  // K4: out = vB . P^T, f32. M=512, N=1024, K=1024.
  gemm_glds<1024, 1024, 1024, 1024, false, 8, 4, BN><<<dim3(8, 4, BN), 256, 0, stream>>>(
      vB, SP, (void*)out, 1.0f,
      (size_t)CC * LN, (size_t)LN * LN, (size_t)CC * LN);
}